// Round 15
// baseline (236.878 us; speedup 1.0000x reference)
//
#include <hip/hip_runtime.h>
#include <hip/hip_bf16.h>
#include <math.h>

#define N_NODES 50000
#define N_EDGES 800000
#define IN_F 256
#define HF 256
#define NHEAD 4
#define OF 64
#define NPAD 50176
#define CAP 96          // max degree (Poisson(16): P(>=96) ~ 1e-40)
#define CONV_BLOCKS 782 // 782*64 = 50048 rows
#define FILL_BLOCKS 1250
#define TOT_BLOCKS (CONV_BLOCKS + FILL_BLOCKS)

typedef __attribute__((ext_vector_type(8))) short short8;
typedef __attribute__((ext_vector_type(4))) float f32x4;

__device__ __forceinline__ ushort f32_to_bf16(float x) {
  unsigned u = __float_as_uint(x);
  u += 0x7FFFu + ((u >> 16) & 1u);   // RNE
  return (ushort)(u >> 16);
}
__device__ __forceinline__ float bfl(unsigned u) { return __uint_as_float(u << 16); }
__device__ __forceinline__ float bfh(unsigned u) { return __uint_as_float(u & 0xFFFF0000u); }

// ---- prep: WT[n][k]=bf16(W[k][n]); WL16[q][k]=bf16(sum_f W[k][h*64+f]*attn[h][f]);
//      zero cnt ----
__global__ __launch_bounds__(256) void prep(const float* __restrict__ W,
                                            const float* __restrict__ al,
                                            const float* __restrict__ ar,
                                            ushort* __restrict__ WT,
                                            ushort* __restrict__ WL16,
                                            int* __restrict__ cnt) {
  int i = blockIdx.x * blockDim.x + threadIdx.x;
  int stride = gridDim.x * blockDim.x;
  for (int j = i; j < IN_F * HF; j += stride) {
    int n = j >> 8, k = j & 255;
    WT[j] = f32_to_bf16(W[k * HF + n]);
  }
  for (int j = i; j < 16 * IN_F; j += stride) {
    int q = j >> 8, k = j & 255;
    float s = 0.f;
    if (q < 8) {
      int h = q & 3;
      const float* av = (q >= 4) ? ar : al;
      for (int f = 0; f < OF; ++f) s += W[k * HF + h * OF + f] * av[h * OF + f];
    }
    WL16[j] = f32_to_bf16(s);
  }
  for (int j = i; j < NPAD; j += stride) cnt[j] = 0;
}

// ---- fusedA: conv role = feat->bf16 + el/er via MFMA(WL16); fill role = CSR ----
__global__ __launch_bounds__(256) void fusedA(const float* __restrict__ feat,
                                              const ushort* __restrict__ WL16,
                                              const int* __restrict__ src,
                                              const int* __restrict__ dst,
                                              ushort* __restrict__ feat_bf,
                                              float* __restrict__ el,
                                              float* __restrict__ er,
                                              int* __restrict__ cnt,
                                              int* __restrict__ csr_src) {
  int tid = threadIdx.x;
  int i = blockIdx.x;
  int g0 = (int)(((long)i * CONV_BLOCKS) / TOT_BLOCKS);
  int g1 = (int)(((long)(i + 1) * CONV_BLOCKS) / TOT_BLOCKS);

  if (g1 == g0) {
    // ---- fill role ----
    int fb = i - g0;
    int stride = FILL_BLOCKS * 256;
    for (int e = fb * 256 + tid; e < N_EDGES; e += stride) {
      int s = __builtin_nontemporal_load(&src[e]);
      int d = dst[e];
      int p = atomicAdd(&cnt[d], 1);
      if (p < CAP) csr_src[d * CAP + p] = s;
    }
    return;
  }

  // ---- conv role: wave handles 16 rows ----
  int w = tid >> 6, lane = tid & 63;
  int rl = lane & 15, khalf = lane >> 4;
  int base = g0 * 64 + w * 16;
  int row = base + rl;
  int rowc = min(row, N_NODES - 1);
  f32x4 acc = (f32x4){0.f, 0.f, 0.f, 0.f};
#pragma unroll 2
  for (int kt = 0; kt < 8; ++kt) {
    int k0 = kt * 32 + khalf * 8;
    const float* ap = feat + (size_t)rowc * IN_F + k0;
    float4 lo = *(const float4*)(ap);
    float4 hi = *(const float4*)(ap + 4);
    union { short8 s; unsigned u[4]; } cv;
    cv.u[0] = __builtin_amdgcn_perm(__float_as_uint(lo.y), __float_as_uint(lo.x), 0x07060302);
    cv.u[1] = __builtin_amdgcn_perm(__float_as_uint(lo.w), __float_as_uint(lo.z), 0x07060302);
    cv.u[2] = __builtin_amdgcn_perm(__float_as_uint(hi.y), __float_as_uint(hi.x), 0x07060302);
    cv.u[3] = __builtin_amdgcn_perm(__float_as_uint(hi.w), __float_as_uint(hi.z), 0x07060302);
    if (row < N_NODES)
      *(short8*)(feat_bf + (size_t)row * IN_F + k0) = cv.s;
    short8 b = *(const short8*)(WL16 + (size_t)rl * IN_F + k0);
    acc = __builtin_amdgcn_mfma_f32_16x16x32_bf16(cv.s, b, acc, 0, 0, 0);
  }
  // acc: logit[row = base+khalf*4+j][q = rl]; q<4 -> el head q, 4..7 -> er
  if (rl < 8) {
#pragma unroll
    for (int j = 0; j < 4; ++j) {
      int r = base + khalf * 4 + j;
      if (r < N_NODES) {
        if (rl < 4) el[r * NHEAD + rl] = acc[j];
        else        er[r * NHEAD + (rl - 4)] = acc[j];
      }
    }
  }
}

// ---- aggmm: 16 nodes/block. Phase 1: PER-HEAD gather-aggregate into swizzled
//      LDS agg[4][16][256] bf16. Phase 2: wave w = head w mini-GEMM vs WT. ----
__global__ __launch_bounds__(256) void aggmm(const int* __restrict__ cnt,
                                             const int* __restrict__ csr_src,
                                             const float* __restrict__ el,
                                             const float* __restrict__ er,
                                             const ushort* __restrict__ feat_bf,
                                             const ushort* __restrict__ WT,
                                             float* __restrict__ out) {
  __shared__ char lds[32768];         // agg [4 heads][16 nodes][256 bf16], swizzled
  int tid = threadIdx.x;
  int w = tid >> 6, lane = tid & 63;
  int n0 = blockIdx.x * 16;
  int half = lane >> 5, l5 = lane & 31;
  int c = l5 << 3;                    // this lane's 8 columns

  // ---- phase 1: each wave aggregates its 4 nodes, all 4 heads ----
  for (int q = 0; q < 4; ++q) {
    int nl = w * 4 + q;
    int n = n0 + nl;
    f32x4 ern = *(const f32x4*)&er[(size_t)n * NHEAD];
    int j0 = n * CAP;
    int j1 = j0 + min(cnt[n], CAP);
    float ac[4][8];
#pragma unroll
    for (int h = 0; h < 4; ++h)
#pragma unroll
      for (int k = 0; k < 8; ++k) ac[h][k] = 0.f;
    f32x4 dn = (f32x4){0.f, 0.f, 0.f, 0.f};
    for (int j = j0 + half; j < j1; j += 2) {
      int s = __builtin_nontemporal_load(&csr_src[j]);
      f32x4 elv = *(const f32x4*)&el[(size_t)s * NHEAD];
      float av[4];
#pragma unroll
      for (int h = 0; h < 4; ++h) {
        float x = elv[h] + ern[h];
        x = x > 0.f ? x : 0.2f * x;
        av[h] = __expf(x);
        dn[h] += av[h];
      }
      uint4 u = *(const uint4*)(feat_bf + (size_t)s * IN_F + c);
      float f0 = bfl(u.x), f1 = bfh(u.x), f2 = bfl(u.y), f3 = bfh(u.y);
      float f4 = bfl(u.z), f5 = bfh(u.z), f6 = bfl(u.w), f7 = bfh(u.w);
#pragma unroll
      for (int h = 0; h < 4; ++h) {
        ac[h][0] += f0 * av[h]; ac[h][1] += f1 * av[h];
        ac[h][2] += f2 * av[h]; ac[h][3] += f3 * av[h];
        ac[h][4] += f4 * av[h]; ac[h][5] += f5 * av[h];
        ac[h][6] += f6 * av[h]; ac[h][7] += f7 * av[h];
      }
    }
    // merge the two half-wave partials
#pragma unroll
    for (int h = 0; h < 4; ++h) {
      dn[h] += __shfl_xor(dn[h], 32);
#pragma unroll
      for (int k = 0; k < 8; ++k) ac[h][k] += __shfl_xor(ac[h][k], 32);
    }
    if (half == 0) {
#pragma unroll
      for (int h = 0; h < 4; ++h) {
        float inv = dn[h] > 0.f ? 1.0f / dn[h] : 0.f;   // deg-0 -> 0 (matches ref)
        union { ushort us[8]; short8 s8; } o;
#pragma unroll
        for (int k = 0; k < 8; ++k) o.us[k] = f32_to_bf16(ac[h][k] * inv);
        int r = h * 16 + nl;
        *(short8*)(lds + r * 512 + ((l5 ^ (r & 7)) << 4)) = o.s8;
      }
    }
  }
  __syncthreads();

  // ---- phase 2: wave w computes output head w: agg_w(16x256) @ W cols ----
  int rl = lane & 15, khalf = lane >> 4;
  f32x4 acc[4];
#pragma unroll
  for (int n = 0; n < 4; ++n) acc[n] = (f32x4){0.f, 0.f, 0.f, 0.f};
#pragma unroll
  for (int kt = 0; kt < 8; ++kt) {
    int r = w * 16 + rl;
    int slot = kt * 4 + khalf;
    short8 a = *(const short8*)(lds + r * 512 + ((slot ^ (r & 7)) << 4));
#pragma unroll
    for (int n = 0; n < 4; ++n) {
      int col = w * 64 + n * 16 + rl;
      short8 b = *(const short8*)(WT + (size_t)col * IN_F + kt * 32 + khalf * 8);
      acc[n] = __builtin_amdgcn_mfma_f32_16x16x32_bf16(a, b, acc[n], 0, 0, 0);
    }
  }
  // D layout: col = rl-part of col, node row = khalf*4 + j
#pragma unroll
  for (int n = 0; n < 4; ++n) {
    int col = w * 64 + n * 16 + rl;
#pragma unroll
    for (int j = 0; j < 4; ++j) {
      int node = n0 + khalf * 4 + j;
      __builtin_nontemporal_store(acc[n][j], &out[(size_t)node * HF + col]);
    }
  }
}

extern "C" void kernel_launch(void* const* d_in, const int* in_sizes, int n_in,
                              void* d_out, int out_size, void* d_ws, size_t ws_size,
                              hipStream_t stream) {
  const float* feat = (const float*)d_in[0];
  const int*   src  = (const int*)d_in[1];
  const int*   dst  = (const int*)d_in[2];
  const float* W    = (const float*)d_in[3];
  const float* al   = (const float*)d_in[4];
  const float* ar   = (const float*)d_in[5];
  float* out = (float*)d_out;

  char* ws = (char*)d_ws;
  ushort* feat_bf = (ushort*)(ws);                    // 25,600,000 B
  int*    csr_src = (int*)(ws + 26000000);            // 19,200,000 B
  int*    cnt     = (int*)(ws + 45400000);            //    200,704 B
  float*  el      = (float*)(ws + 45700000);          //    800,000 B
  float*  er      = (float*)(ws + 46500000);          //    800,000 B
  ushort* WT      = (ushort*)(ws + 47300000);         //    131,072 B
  ushort* WL16    = (ushort*)(ws + 47500000);         //      8,192 B

  prep<<<512, 256, 0, stream>>>(W, al, ar, WT, WL16, cnt);
  fusedA<<<TOT_BLOCKS, 256, 0, stream>>>(feat, WL16, src, dst, feat_bf, el, er,
                                         cnt, csr_src);
  aggmm<<<N_NODES / 16, 256, 0, stream>>>(cnt, csr_src, el, er, feat_bf, WT, out);
}

// Round 16
// 131.815 us; speedup vs baseline: 1.7971x; 1.7971x over previous
//
#include <hip/hip_runtime.h>
#include <hip/hip_bf16.h>
#include <math.h>

#define N_NODES 50000
#define N_EDGES 800000
#define IN_F 256
#define HF 256      // NUM_HEADS * OUT_FEATS
#define NHEAD 4
#define OF 64
#define NPAD 50176
#define CAP 96          // max degree capacity (Poisson(16): P(>=96) ~ 1e-40)
#define MPAD 50048      // 782 * 64
#define GEMM_BLOCKS 782
#define FILL_BLOCKS 1250
#define TOT_BLOCKS (GEMM_BLOCKS + FILL_BLOCKS)

typedef __attribute__((ext_vector_type(8))) short short8;
typedef __attribute__((ext_vector_type(4))) float f32x4;

// ---- explicit bf16 conversions ----
__device__ __forceinline__ ushort f32_to_bf16(float x) {
  unsigned u = __float_as_uint(x);
  u += 0x7FFFu + ((u >> 16) & 1u);   // round-to-nearest-even
  return (ushort)(u >> 16);
}
__device__ __forceinline__ float bfl(unsigned u) { return __uint_as_float(u << 16); }
__device__ __forceinline__ float bfh(unsigned u) { return __uint_as_float(u & 0xFFFF0000u); }

// async global->LDS, 16B per lane
__device__ __forceinline__ void gload_lds16(const void* g, void* l) {
  __builtin_amdgcn_global_load_lds(
      (const __attribute__((address_space(1))) unsigned int*)g,
      (__attribute__((address_space(3))) unsigned int*)l, 16, 0, 0);
}

// ---- prep: W -> W^T bf16, zero cnt ----
__global__ __launch_bounds__(256) void prep(const float* __restrict__ W,
                                            ushort* __restrict__ WT,
                                            int* __restrict__ cnt) {
  int i = blockIdx.x * blockDim.x + threadIdx.x;
  int stride = gridDim.x * blockDim.x;
  for (int j = i; j < IN_F * HF; j += stride) {
    int n = j >> 8, k = j & 255;                 // WT[n][k] = W[k][n]
    WT[j] = f32_to_bf16(W[k * HF + n]);
  }
  for (int j = i; j < NPAD; j += stride) cnt[j] = 0;
}

// ---- fused, Bresenham-interleaved roles.
//      GEMM role: BM=64, BN=256, BK=64; A double-buffered (2x16KB swizzled
//      global_load_lds), B direct from L2-resident WT; 4 barrier-drains total.
//      FILL role: cnt atomic + fixed-stride CSR scatter. ----
__global__ __launch_bounds__(256) void fused_gf(const float* __restrict__ A,
                                                const ushort* __restrict__ BT,
                                                const float* __restrict__ al,
                                                const float* __restrict__ ar,
                                                ushort* __restrict__ C,
                                                float* __restrict__ el,
                                                float* __restrict__ er,
                                                const int* __restrict__ src,
                                                const int* __restrict__ dst,
                                                int* __restrict__ cnt,
                                                int* __restrict__ csr_src) {
  __shared__ char lds[32768];               // A double buffer: 2 x 16KB
  int tid = threadIdx.x;
  int i = blockIdx.x;
  int g0 = (int)(((long)i * GEMM_BLOCKS) / TOT_BLOCKS);
  int g1 = (int)(((long)(i + 1) * GEMM_BLOCKS) / TOT_BLOCKS);

  if (g1 == g0) {
    // ---------------- fill path ----------------
    int fb = i - g0;
    int stride = FILL_BLOCKS * 256;
    for (int e = fb * 256 + tid; e < N_EDGES; e += stride) {
      int s = __builtin_nontemporal_load(&src[e]);
      int d = dst[e];
      int p = atomicAdd(&cnt[d], 1);
      if (p < CAP) csr_src[d * CAP + p] = s;
    }
    return;
  }

  // ---------------- GEMM path (tile g0) ----------------
  char* As0 = lds;
  char* As1 = lds + 16384;
  int w = tid >> 6, lane = tid & 63;        // w = head (N-quarter)
  int brow = g0 * 64;
  int rl = lane & 15, khalf = lane >> 4;    // khalf 0..3
  f32x4 acc[4][4];
#pragma unroll
  for (int m = 0; m < 4; ++m)
#pragma unroll
    for (int n = 0; n < 4; ++n) acc[m][n] = (f32x4){0.f, 0.f, 0.f, 0.f};

  // stage 64x64 f32 K-tile (16KB): 4 instrs/wave; 16 16B-slots/row, slot^=row&15
#define STAGE_A(buf, k0)                                                     \
  {                                                                          \
    _Pragma("unroll")                                                        \
    for (int part = 0; part < 4; ++part) {                                   \
      int ii = w * 4 + part;                                                 \
      int d = ii * 1024 + lane * 16;                                         \
      int trow = d >> 8;                                                     \
      int slot = (d >> 4) & 15;                                              \
      int srcslot = slot ^ (trow & 15);                                      \
      int ga = min(brow + trow, N_NODES - 1);                                \
      gload_lds16(A + (size_t)ga * IN_F + (k0) + srcslot * 4, (buf) + d);    \
    }                                                                        \
  }

  STAGE_A(As0, 0);
  __syncthreads();

  for (int kt = 0; kt < 4; ++kt) {
    int kbase = kt * 64;
    char* cur = (kt & 1) ? As1 : As0;
    char* nxt = (kt & 1) ? As0 : As1;
    if (kt < 3) STAGE_A(nxt, kbase + 64);   // prefetch next macro-tile
#pragma unroll
    for (int ss = 0; ss < 2; ++ss) {
      int k0 = kbase + ss * 32;
      // B fragments direct from L2-resident WT
      short8 b[4];
#pragma unroll
      for (int n = 0; n < 4; ++n) {
        int c = w * 64 + n * 16 + rl;
        b[n] = *(const short8*)(BT + (size_t)c * IN_F + k0 + khalf * 8);
      }
      // A fragments from swizzled LDS + in-register f32->bf16
      short8 a[4];
#pragma unroll
      for (int m = 0; m < 4; ++m) {
        int r = m * 16 + rl;
        int s0 = ss * 8 + khalf * 2, s1 = s0 + 1;
        float4 lo = *(const float4*)(cur + r * 256 + ((s0 ^ (r & 15)) << 4));
        float4 hi = *(const float4*)(cur + r * 256 + ((s1 ^ (r & 15)) << 4));
        union { short8 s; unsigned u[4]; } cv;
        cv.u[0] = __builtin_amdgcn_perm(__float_as_uint(lo.y), __float_as_uint(lo.x), 0x07060302);
        cv.u[1] = __builtin_amdgcn_perm(__float_as_uint(lo.w), __float_as_uint(lo.z), 0x07060302);
        cv.u[2] = __builtin_amdgcn_perm(__float_as_uint(hi.y), __float_as_uint(hi.x), 0x07060302);
        cv.u[3] = __builtin_amdgcn_perm(__float_as_uint(hi.w), __float_as_uint(hi.z), 0x07060302);
        a[m] = cv.s;
      }
#pragma unroll
      for (int m = 0; m < 4; ++m)
#pragma unroll
        for (int n = 0; n < 4; ++n)
          acc[m][n] = __builtin_amdgcn_mfma_f32_16x16x32_bf16(a[m], b[n], acc[m][n], 0, 0, 0);
    }
    __syncthreads();                        // drain prefetch, release cur
  }

  // C write. C/D layout: col = rl, row = khalf*4 + j
#pragma unroll
  for (int m = 0; m < 4; ++m) {
    int r0 = brow + m * 16 + khalf * 4;
#pragma unroll
    for (int n = 0; n < 4; ++n) {
      int col = w * 64 + n * 16 + rl;
#pragma unroll
      for (int j = 0; j < 4; ++j)
        if (r0 + j < N_NODES)
          C[(size_t)(r0 + j) * HF + col] = f32_to_bf16(acc[m][n][j]);
    }
  }

  // fused el/er for head w from f32 accumulators
  float alv[4], arv[4];
#pragma unroll
  for (int n = 0; n < 4; ++n) {
    alv[n] = al[w * OF + n * 16 + rl];
    arv[n] = ar[w * OF + n * 16 + rl];
  }
#pragma unroll
  for (int m = 0; m < 4; ++m) {
    int r0 = brow + m * 16 + khalf * 4;
#pragma unroll
    for (int j = 0; j < 4; ++j) {
      float pl = acc[m][0][j] * alv[0] + acc[m][1][j] * alv[1] +
                 acc[m][2][j] * alv[2] + acc[m][3][j] * alv[3];
      float pr = acc[m][0][j] * arv[0] + acc[m][1][j] * arv[1] +
                 acc[m][2][j] * arv[2] + acc[m][3][j] * arv[3];
#pragma unroll
      for (int off2 = 1; off2 < 16; off2 <<= 1) {
        pl += __shfl_xor(pl, off2);
        pr += __shfl_xor(pr, off2);
      }
      int r = r0 + j;
      if (rl == 0 && r < N_NODES) {
        el[r * NHEAD + w] = pl;
        er[r * NHEAD + w] = pr;
      }
    }
  }
}

// ---- aggregate: wave per node, half-wave per edge, 16B ft loads ----
__global__ __launch_bounds__(256) void aggregate(const int* __restrict__ cnt,
                                                 const int* __restrict__ csr_src,
                                                 const float* __restrict__ el,
                                                 const float* __restrict__ er,
                                                 const ushort* __restrict__ ft,
                                                 float* __restrict__ out) {
  int w = threadIdx.x >> 6, lane = threadIdx.x & 63;
  int n = blockIdx.x * 4 + w;
  if (n >= N_NODES) return;
  int half = lane >> 5, l5 = lane & 31;
  int h = l5 >> 3;        // head for this lane's 8 columns
  int c = l5 << 3;        // column base 0..248
  float erh = er[n * NHEAD + h];
  int j0 = n * CAP;
  int j1 = j0 + min(cnt[n], CAP);
  float a0 = 0.f, a1 = 0.f, a2 = 0.f, a3 = 0.f;
  float a4 = 0.f, a5 = 0.f, a6 = 0.f, a7 = 0.f;
  float den = 0.f;
#pragma unroll 4
  for (int j = j0 + half; j < j1; j += 2) {
    int s = __builtin_nontemporal_load(&csr_src[j]);
    float x = el[s * NHEAD + h] + erh;
    x = x > 0.f ? x : 0.2f * x;
    float a = __expf(x);
    den += a;
    uint4 u = *(const uint4*)(ft + (size_t)s * HF + c);
    a0 += bfl(u.x) * a; a1 += bfh(u.x) * a;
    a2 += bfl(u.y) * a; a3 += bfh(u.y) * a;
    a4 += bfl(u.z) * a; a5 += bfh(u.z) * a;
    a6 += bfl(u.w) * a; a7 += bfh(u.w) * a;
  }
  // merge the two half-wave partials
  den += __shfl_xor(den, 32);
  a0 += __shfl_xor(a0, 32); a1 += __shfl_xor(a1, 32);
  a2 += __shfl_xor(a2, 32); a3 += __shfl_xor(a3, 32);
  a4 += __shfl_xor(a4, 32); a5 += __shfl_xor(a5, 32);
  a6 += __shfl_xor(a6, 32); a7 += __shfl_xor(a7, 32);
  if (half == 0) {
    float inv = den > 0.f ? 1.0f / den : 0.f;   // degree-0 -> 0 (matches ref)
    f32x4 r0 = {a0 * inv, a1 * inv, a2 * inv, a3 * inv};
    f32x4 r1 = {a4 * inv, a5 * inv, a6 * inv, a7 * inv};
    __builtin_nontemporal_store(r0, (f32x4*)&out[(size_t)n * HF + c]);
    __builtin_nontemporal_store(r1, (f32x4*)&out[(size_t)n * HF + c + 4]);
  }
}

extern "C" void kernel_launch(void* const* d_in, const int* in_sizes, int n_in,
                              void* d_out, int out_size, void* d_ws, size_t ws_size,
                              hipStream_t stream) {
  const float* feat = (const float*)d_in[0];
  const int*   src  = (const int*)d_in[1];
  const int*   dst  = (const int*)d_in[2];
  const float* W    = (const float*)d_in[3];
  const float* al   = (const float*)d_in[4];
  const float* ar   = (const float*)d_in[5];
  float* out = (float*)d_out;

  char* ws = (char*)d_ws;
  ushort* ft_bf   = (ushort*)(ws);                    // 25,624,576 B (MPAD rows)
  int*    csr_src = (int*)(ws + 26000000);            // 19,200,000 B (50000*96*4)
  int*    cnt     = (int*)(ws + 45400000);            //    200,704 B
  float*  el      = (float*)(ws + 45700000);          //    800,000 B
  float*  er      = (float*)(ws + 46500000);          //    800,000 B
  ushort* WT      = (ushort*)(ws + 47300000);         //    131,072 B

  prep<<<512, 256, 0, stream>>>(W, WT, cnt);
  fused_gf<<<TOT_BLOCKS, 256, 0, stream>>>(feat, WT, al, ar, ft_bf,
                                           el, er, src, dst, cnt, csr_src);
  aggregate<<<(N_NODES + 3) / 4, 256, 0, stream>>>(cnt, csr_src, el, er, ft_bf, out);
}